// Round 20
// baseline (198.760 us; speedup 1.0000x reference)
//
#include <hip/hip_runtime.h>
#include <hip/hip_bf16.h>

#define S_LEN 2048
#define NHEADS 32
#define NKV 8
#define HD 128
#define QK_SCALE 0.08838834764831845f           // 1/sqrt(128)
#define LOG2E 1.4426950408889634f
#define QK_SCALE2 (QK_SCALE * LOG2E)            // folded into Q (log2 domain)
#define DTHR 11.5416f                           // defer-max threshold (8 nats in log2)

#define BQ 128                // q rows per block (4 waves x 2 strips x 16)
#define BK 32                 // kv rows per tile
#define NQT (S_LEN / BQ)      // 16 q tiles
#define QSTR (NHEADS * HD)    // 4096
#define KSTR (NKV * HD)       // 1024

#define K_STRIDE 136          // LDS row stride (shorts) — R10-proven
#define VT_STRIDE 40          // R10-proven
#define P_STRIDE 40

typedef __attribute__((ext_vector_type(8))) short bf16x8;
typedef __attribute__((ext_vector_type(4))) float f32x4;
typedef __attribute__((ext_vector_type(4))) unsigned u32x4;
typedef __attribute__((ext_vector_type(2))) unsigned u32x2;

__device__ inline unsigned cvt_pk_bf16(float lo, float hi) {
    unsigned r;
    asm("v_cvt_pk_bf16_f32 %0, %1, %2" : "=v"(r) : "v"(lo), "v"(hi));
    return r;
}
__device__ inline bf16x8 as_bf16x8(u32x4 v) {
    union { u32x4 u; bf16x8 b; } c; c.u = v; return c.b;
}

// ---- pre-pass 1: K [s][kv*hd] f32 -> Kbf [kv][s][hd] bf16 (rows contiguous) ----
__global__ __launch_bounds__(256) void prep_k(const float* __restrict__ K,
                                              short* __restrict__ Kbf) {
    int g = blockIdx.x * 256 + threadIdx.x;     // [0, S*KV*16)
    int chunk = g & 15, kvh = (g >> 4) & 7, s = g >> 7;
    const float* in = K + (size_t)s * KSTR + kvh * HD + chunk * 8;
    f32x4 a = *(const f32x4*)in;
    f32x4 b = *(const f32x4*)(in + 4);
    u32x4 t;
    t[0] = cvt_pk_bf16(a[0], a[1]); t[1] = cvt_pk_bf16(a[2], a[3]);
    t[2] = cvt_pk_bf16(b[0], b[1]); t[3] = cvt_pk_bf16(b[2], b[3]);
    *(u32x4*)(Kbf + ((size_t)kvh * S_LEN + s) * HD + chunk * 8) = t;
}

// ---- pre-pass 2: V [s][kv*hd] f32 -> Vtb [kv][hd][s] bf16 (transposed) ----
// R8-verified (both u32x4 halves stored; aligned LDS tile).
__global__ __launch_bounds__(256) void prep_v(const float* __restrict__ V,
                                              short* __restrict__ Vtb) {
    __shared__ short Ts[64][72];                 // 144B row stride: 16B-aligned
    int b = blockIdx.x;                          // 512 = kvh(8) x db(2) x sb(32)
    int sb = b & 31, db = (b >> 5) & 1, kvh = b >> 6;
    int t = threadIdx.x, r = t >> 2, c0 = (t & 3) * 16;

    const float* in = V + (size_t)(sb * 64 + r) * KSTR + kvh * HD + db * 64 + c0;
    f32x4 a0 = *(const f32x4*)in,        a1 = *(const f32x4*)(in + 4);
    f32x4 a2 = *(const f32x4*)(in + 8),  a3 = *(const f32x4*)(in + 12);
    u32x4 t0;
    t0[0] = cvt_pk_bf16(a0[0], a0[1]); t0[1] = cvt_pk_bf16(a0[2], a0[3]);
    t0[2] = cvt_pk_bf16(a1[0], a1[1]); t0[3] = cvt_pk_bf16(a1[2], a1[3]);
    *(u32x4*)&Ts[r][c0] = t0;
    t0[0] = cvt_pk_bf16(a2[0], a2[1]); t0[1] = cvt_pk_bf16(a2[2], a2[3]);
    t0[2] = cvt_pk_bf16(a3[0], a3[1]); t0[3] = cvt_pk_bf16(a3[2], a3[3]);
    *(u32x4*)&Ts[r][c0 + 8] = t0;
    __syncthreads();

    alignas(16) short tmp[16];
    #pragma unroll
    for (int j = 0; j < 16; ++j) tmp[j] = Ts[c0 + j][r];
    short* dst = Vtb + ((size_t)(kvh * HD + db * 64 + r)) * S_LEN + sb * 64 + c0;
    *(u32x4*)dst       = *(u32x4*)&tmp[0];
    *(u32x4*)(dst + 8) = *(u32x4*)&tmp[8];
}

// ---- main: R17 core, 2 q-strips per wave (K/V LDS reads + staging amortized 2x) ----
__global__ __launch_bounds__(256) void attn_fwd(
    const float* __restrict__ Q, const short* __restrict__ Kbf,
    const short* __restrict__ Vtb, const float* __restrict__ SL,
    float* __restrict__ O)
{
    const int bx   = blockIdx.x;
    const int h    = bx & (NHEADS - 1);
    const int qt   = (NQT - 1) - (bx >> 5);     // heavy q-tiles dispatch first
    const int kvh  = h >> 2;
    const float slope  = SL[h];
    const float slope2 = slope * LOG2E;

    const int tid  = threadIdx.x;
    const int lane = tid & 63;
    const int w    = tid >> 6;                  // wave 0..3
    const int l16  = lane & 15;
    const int lq   = lane >> 4;

    __shared__ short Ks[2][BK * K_STRIDE];     // double-buffered K [k][d]
    __shared__ short VTs[2][HD * VT_STRIDE];   // double-buffered V^T [d][k]
    __shared__ short Ps[4][32 * P_STRIDE];     // per-wave P, 2 strips x 16 q

    const int qrow0 = qt * BQ + w * 32;        // strip A rows qrow0..+15, B +16..+31
    const int qA    = qrow0 + l16;
    const int qB    = qA + 16;

    // ---- Q fragments for both strips (B-operand; scale*log2e folded in) ----
    bf16x8 qfA[4], qfB[4];
    #pragma unroll
    for (int st = 0; st < 2; ++st) {
        const float* qp = Q + (size_t)(st ? qB : qA) * QSTR + h * HD + lq * 8;
        #pragma unroll
        for (int d0 = 0; d0 < 4; ++d0) {
            f32x4 a = *(const f32x4*)(qp + d0 * 32);
            f32x4 b = *(const f32x4*)(qp + d0 * 32 + 4);
            u32x4 t;
            t[0] = cvt_pk_bf16(a[0] * QK_SCALE2, a[1] * QK_SCALE2);
            t[1] = cvt_pk_bf16(a[2] * QK_SCALE2, a[3] * QK_SCALE2);
            t[2] = cvt_pk_bf16(b[0] * QK_SCALE2, b[1] * QK_SCALE2);
            t[3] = cvt_pk_bf16(b[2] * QK_SCALE2, b[3] * QK_SCALE2);
            if (st) qfB[d0] = as_bf16x8(t); else qfA[d0] = as_bf16x8(t);
        }
    }
    bf16x8 onesf;
    #pragma unroll
    for (int j = 0; j < 8; ++j) onesf[j] = (short)0x3f80;

    // accumulators per strip: O^T fragments + l-sums + running max
    f32x4 accA[8], accB[8];
    #pragma unroll
    for (int t = 0; t < 8; ++t) {
        accA[t] = (f32x4){0.f, 0.f, 0.f, 0.f};
        accB[t] = (f32x4){0.f, 0.f, 0.f, 0.f};
    }
    f32x4 sumsA = (f32x4){0.f,0.f,0.f,0.f}, sumsB = (f32x4){0.f,0.f,0.f,0.f};
    float mA = -1e30f, mB = -1e30f;

    const int kv_end = qt * BQ + BQ;
    int kb_start = 0;
    {   // ALiBi far-tile skip using the block's minimum q row
        float th = (float)(qt * BQ) - 31.0f - 45.0f / slope;
        int t = (int)floorf(th);
        kb_start = (t < 0) ? 0 : (((t >> 5) + 1) << 5);
    }

    // ---- staging thread mapping: bf16 sources, 16B chunks (R15-proven) ----
    const int sr  = tid >> 4, scc = tid & 15;
    const int vd  = tid & 127, vrb = (tid >> 7) * 8;
    const short* Kst = Kbf + (size_t)kvh * S_LEN * HD + scc * 8;
    const short* Vst = Vtb + (size_t)(kvh * HD + vd) * S_LEN;

    u32x4 kreg[2], vreg[2];

    auto load_regs = [&](int kb) {
        #pragma unroll
        for (int s = 0; s < 2; ++s)
            kreg[s] = *(const u32x4*)(Kst + (size_t)(kb + sr + s * 16) * HD);
        #pragma unroll
        for (int s = 0; s < 2; ++s)
            vreg[s] = *(const u32x4*)(Vst + kb + vrb + s * 16);
    };
    auto store_tile = [&](int b) {
        #pragma unroll
        for (int s = 0; s < 2; ++s)
            *(u32x4*)&Ks[b][(sr + s * 16) * K_STRIDE + scc * 8] = kreg[s];
        #pragma unroll
        for (int s = 0; s < 2; ++s)
            *(u32x4*)&VTs[b][vd * VT_STRIDE + vrb + s * 16] = vreg[s];
    };

    load_regs(kb_start);
    store_tile(0);
    int cur = 0;

    for (int kb = kb_start; kb < kv_end; kb += BK) {
        asm volatile("s_waitcnt lgkmcnt(0)\n\ts_barrier" ::: "memory");

        const bool has_next = (kb + BK) < kv_end;
        if (has_next) load_regs(kb + BK);

        const bool liveA = (kb <= qrow0 + 15) &&
                           (slope * (float)(qrow0 - kb - 31) < 45.0f);
        const bool liveB = (kb <= qrow0 + 31) &&
                           (slope * (float)(qrow0 + 16 - kb - 31) < 45.0f);

        if (liveA || liveB) {
            const short* Kc = &Ks[cur][0];
            const short* Vc = &VTs[cur][0];

            // ---- S^T = K·Q^T : kf loaded ONCE, feeds both strips ----
            f32x4 sA0 = (f32x4){0.f,0.f,0.f,0.f}, sA1 = (f32x4){0.f,0.f,0.f,0.f};
            f32x4 sB0 = (f32x4){0.f,0.f,0.f,0.f}, sB1 = (f32x4){0.f,0.f,0.f,0.f};
            #pragma unroll
            for (int d0 = 0; d0 < 4; ++d0) {
                bf16x8 kf0 = *(const bf16x8*)&Kc[l16 * K_STRIDE + d0 * 32 + lq * 8];
                bf16x8 kf1 = *(const bf16x8*)&Kc[(16 + l16) * K_STRIDE + d0 * 32 + lq * 8];
                if (liveA) {
                    sA0 = __builtin_amdgcn_mfma_f32_16x16x32_bf16(kf0, qfA[d0], sA0, 0, 0, 0);
                    sA1 = __builtin_amdgcn_mfma_f32_16x16x32_bf16(kf1, qfA[d0], sA1, 0, 0, 0);
                }
                if (liveB) {
                    sB0 = __builtin_amdgcn_mfma_f32_16x16x32_bf16(kf0, qfB[d0], sB0, 0, 0, 0);
                    sB1 = __builtin_amdgcn_mfma_f32_16x16x32_bf16(kf1, qfB[d0], sB1, 0, 0, 0);
                }
            }

            short* PsW = &Ps[w][0];
            bool pvA = false, pvB = false;

            // ---- strip A softmax ----
            if (liveA) {
                const int kq0 = kb + 4 * lq - qA;
                float s[8];
                #pragma unroll
                for (int i = 0; i < 4; ++i) {
                    int d0i = kq0 + i, d1i = kq0 + 16 + i;
                    float b0 = __builtin_fmaf(slope2, (float)d0i, sA0[i]);
                    float b1 = __builtin_fmaf(slope2, (float)d1i, sA1[i]);
                    s[i]     = (d0i > 0) ? -1e30f : b0;
                    s[i + 4] = (d1i > 0) ? -1e30f : b1;
                }
                float lm = fmaxf(fmaxf(fmaxf(s[0], s[1]), fmaxf(s[2], s[3])),
                                 fmaxf(fmaxf(s[4], s[5]), fmaxf(s[6], s[7])));
                if (__any(lm > mA + DTHR)) {
                    float rm = lm;
                    rm = fmaxf(rm, __shfl_xor(rm, 16));
                    rm = fmaxf(rm, __shfl_xor(rm, 32));
                    if (rm > mA + DTHR) {
                        float alpha = exp2f(mA - rm);
                        mA = rm;
                        sumsA[0] *= alpha; sumsA[1] *= alpha;
                        sumsA[2] *= alpha; sumsA[3] *= alpha;
                        #pragma unroll
                        for (int t = 0; t < 8; ++t) {
                            accA[t][0] *= alpha; accA[t][1] *= alpha;
                            accA[t][2] *= alpha; accA[t][3] *= alpha;
                        }
                    }
                }
                float p[8];
                #pragma unroll
                for (int j = 0; j < 8; ++j) p[j] = exp2f(s[j] - mA);
                u32x2 pa, pb;
                pa[0] = cvt_pk_bf16(p[0], p[1]); pa[1] = cvt_pk_bf16(p[2], p[3]);
                pb[0] = cvt_pk_bf16(p[4], p[5]); pb[1] = cvt_pk_bf16(p[6], p[7]);
                *(u32x2*)&PsW[l16 * P_STRIDE + 4 * lq]      = pa;
                *(u32x2*)&PsW[l16 * P_STRIDE + 16 + 4 * lq] = pb;
                pvA = true;
            }
            // ---- strip B softmax ----
            if (liveB) {
                const int kq0 = kb + 4 * lq - qB;
                float s[8];
                #pragma unroll
                for (int i = 0; i < 4; ++i) {
                    int d0i = kq0 + i, d1i = kq0 + 16 + i;
                    float b0 = __builtin_fmaf(slope2, (float)d0i, sB0[i]);
                    float b1 = __builtin_fmaf(slope2, (float)d1i, sB1[i]);
                    s[i]     = (d0i > 0) ? -1e30f : b0;
                    s[i + 4] = (d1i > 0) ? -1e30f : b1;
                }
                float lm = fmaxf(fmaxf(fmaxf(s[0], s[1]), fmaxf(s[2], s[3])),
                                 fmaxf(fmaxf(s[4], s[5]), fmaxf(s[6], s[7])));
                if (__any(lm > mB + DTHR)) {
                    float rm = lm;
                    rm = fmaxf(rm, __shfl_xor(rm, 16));
                    rm = fmaxf(rm, __shfl_xor(rm, 32));
                    if (rm > mB + DTHR) {
                        float alpha = exp2f(mB - rm);
                        mB = rm;
                        sumsB[0] *= alpha; sumsB[1] *= alpha;
                        sumsB[2] *= alpha; sumsB[3] *= alpha;
                        #pragma unroll
                        for (int t = 0; t < 8; ++t) {
                            accB[t][0] *= alpha; accB[t][1] *= alpha;
                            accB[t][2] *= alpha; accB[t][3] *= alpha;
                        }
                    }
                }
                float p[8];
                #pragma unroll
                for (int j = 0; j < 8; ++j) p[j] = exp2f(s[j] - mB);
                u32x2 pa, pb;
                pa[0] = cvt_pk_bf16(p[0], p[1]); pa[1] = cvt_pk_bf16(p[2], p[3]);
                pb[0] = cvt_pk_bf16(p[4], p[5]); pb[1] = cvt_pk_bf16(p[6], p[7]);
                *(u32x2*)&PsW[(16 + l16) * P_STRIDE + 4 * lq]      = pa;
                *(u32x2*)&PsW[(16 + l16) * P_STRIDE + 16 + 4 * lq] = pb;
                pvB = true;
            }

            asm volatile("s_waitcnt lgkmcnt(0)" ::: "memory");
            bf16x8 pfA, pfB;
            if (pvA) pfA = *(const bf16x8*)&PsW[l16 * P_STRIDE + lq * 8];
            if (pvB) pfB = *(const bf16x8*)&PsW[(16 + l16) * P_STRIDE + lq * 8];

            if (pvA) sumsA = __builtin_amdgcn_mfma_f32_16x16x32_bf16(onesf, pfA, sumsA, 0, 0, 0);
            if (pvB) sumsB = __builtin_amdgcn_mfma_f32_16x16x32_bf16(onesf, pfB, sumsB, 0, 0, 0);

            // ---- PV: vf loaded ONCE per nt, feeds both strips ----
            #pragma unroll
            for (int nt = 0; nt < 8; ++nt) {
                bf16x8 vf = *(const bf16x8*)&Vc[(nt * 16 + l16) * VT_STRIDE + lq * 8];
                if (pvA) accA[nt] = __builtin_amdgcn_mfma_f32_16x16x32_bf16(vf, pfA, accA[nt], 0, 0, 0);
                if (pvB) accB[nt] = __builtin_amdgcn_mfma_f32_16x16x32_bf16(vf, pfB, accB[nt], 0, 0, 0);
            }
        }

        if (has_next) store_tile(cur ^ 1);
        cur ^= 1;
    }

    // ---- epilogue: both strips ----
    {
        float rlA = 1.0f / sumsA[0];
        float* opA = O + (size_t)qA * QSTR + h * HD + 4 * lq;
        #pragma unroll
        for (int nt = 0; nt < 8; ++nt) {
            f32x4 o = accA[nt];
            o[0] *= rlA; o[1] *= rlA; o[2] *= rlA; o[3] *= rlA;
            *(f32x4*)(opA + nt * 16) = o;
        }
        float rlB = 1.0f / sumsB[0];
        float* opB = O + (size_t)qB * QSTR + h * HD + 4 * lq;
        #pragma unroll
        for (int nt = 0; nt < 8; ++nt) {
            f32x4 o = accB[nt];
            o[0] *= rlB; o[1] *= rlB; o[2] *= rlB; o[3] *= rlB;
            *(f32x4*)(opB + nt * 16) = o;
        }
    }
}

extern "C" void kernel_launch(void* const* d_in, const int* in_sizes, int n_in,
                              void* d_out, int out_size, void* d_ws, size_t ws_size,
                              hipStream_t stream) {
    const float* Q  = (const float*)d_in[0];
    const float* K  = (const float*)d_in[1];
    const float* V  = (const float*)d_in[2];
    const float* SL = (const float*)d_in[3];
    float* O = (float*)d_out;

    short* Kbf = (short*)d_ws;                                   // 4 MB
    short* Vtb = (short*)d_ws + (size_t)NKV * S_LEN * HD;        // 4 MB

    prep_k<<<dim3(1024), dim3(256), 0, stream>>>(K, Kbf);
    prep_v<<<dim3(512),  dim3(256), 0, stream>>>(V, Vtb);
    attn_fwd<<<dim3(NQT * NHEADS), dim3(256), 0, stream>>>(Q, Kbf, Vtb, SL, O);
}

// Round 21
// 91.504 us; speedup vs baseline: 2.1722x; 2.1722x over previous
//
#include <hip/hip_runtime.h>
#include <hip/hip_bf16.h>

#define S_LEN 2048
#define NHEADS 32
#define NKV 8
#define HD 128
#define QK_SCALE 0.08838834764831845f           // 1/sqrt(128)
#define LOG2E 1.4426950408889634f
#define QK_SCALE2 (QK_SCALE * LOG2E)            // folded into Q (log2 domain)
#define DTHR 11.5416f                           // defer-max threshold (8 nats in log2)

#define BQ 64                 // q rows per block (4 waves x 16)
#define BK 32                 // kv rows per tile
#define NQT (S_LEN / BQ)      // 32 q tiles
#define QSTR (NHEADS * HD)    // 4096
#define KSTR (NKV * HD)       // 1024

#define K_STRIDE 136          // LDS row stride (shorts) — R10-proven
#define VT_STRIDE 40          // R10-proven
#define P_STRIDE 40

typedef __attribute__((ext_vector_type(8))) short bf16x8;
typedef __attribute__((ext_vector_type(4))) float f32x4;
typedef __attribute__((ext_vector_type(4))) unsigned u32x4;
typedef __attribute__((ext_vector_type(2))) unsigned u32x2;

__device__ inline unsigned cvt_pk_bf16(float lo, float hi) {
    unsigned r;
    asm("v_cvt_pk_bf16_f32 %0, %1, %2" : "=v"(r) : "v"(lo), "v"(hi));
    return r;
}
__device__ inline bf16x8 as_bf16x8(u32x4 v) {
    union { u32x4 u; bf16x8 b; } c; c.u = v; return c.b;
}

// ---- merged pre-pass: K -> Kbf [kv][s][hd] bf16; V -> Vtb [kv][hd][s] bf16 ----
// One kernel so both halves run concurrently (as two graph nodes they serialize).
__global__ __launch_bounds__(256) void prep_kv(
    const float* __restrict__ K, const float* __restrict__ V,
    short* __restrict__ Kbf, short* __restrict__ Vtb)
{
    __shared__ short Ts[64][72];                 // used by V path only
    const int b = blockIdx.x;
    if (b < 1024) {
        // ---- K path (R15-proven): rows fragment-ready ----
        int g = b * 256 + threadIdx.x;           // [0, S*KV*16)
        int chunk = g & 15, kvh = (g >> 4) & 7, s = g >> 7;
        const float* in = K + (size_t)s * KSTR + kvh * HD + chunk * 8;
        f32x4 a = *(const f32x4*)in;
        f32x4 c = *(const f32x4*)(in + 4);
        u32x4 t;
        t[0] = cvt_pk_bf16(a[0], a[1]); t[1] = cvt_pk_bf16(a[2], a[3]);
        t[2] = cvt_pk_bf16(c[0], c[1]); t[3] = cvt_pk_bf16(c[2], c[3]);
        *(u32x4*)(Kbf + ((size_t)kvh * S_LEN + s) * HD + chunk * 8) = t;
    } else {
        // ---- V path (R8-verified): transpose to [kv][hd][s] ----
        int bv = b - 1024;                       // 512 = kvh(8) x db(2) x sb(32)
        int sb = bv & 31, db = (bv >> 5) & 1, kvh = bv >> 6;
        int t = threadIdx.x, r = t >> 2, c0 = (t & 3) * 16;

        const float* in = V + (size_t)(sb * 64 + r) * KSTR + kvh * HD + db * 64 + c0;
        f32x4 a0 = *(const f32x4*)in,        a1 = *(const f32x4*)(in + 4);
        f32x4 a2 = *(const f32x4*)(in + 8),  a3 = *(const f32x4*)(in + 12);
        u32x4 t0;
        t0[0] = cvt_pk_bf16(a0[0], a0[1]); t0[1] = cvt_pk_bf16(a0[2], a0[3]);
        t0[2] = cvt_pk_bf16(a1[0], a1[1]); t0[3] = cvt_pk_bf16(a1[2], a1[3]);
        *(u32x4*)&Ts[r][c0] = t0;
        t0[0] = cvt_pk_bf16(a2[0], a2[1]); t0[1] = cvt_pk_bf16(a2[2], a2[3]);
        t0[2] = cvt_pk_bf16(a3[0], a3[1]); t0[3] = cvt_pk_bf16(a3[2], a3[3]);
        *(u32x4*)&Ts[r][c0 + 8] = t0;
        __syncthreads();

        alignas(16) short tmp[16];
        #pragma unroll
        for (int j = 0; j < 16; ++j) tmp[j] = Ts[c0 + j][r];
        short* dst = Vtb + ((size_t)(kvh * HD + db * 64 + r)) * S_LEN + sb * 64 + c0;
        *(u32x4*)dst       = *(u32x4*)&tmp[0];
        *(u32x4*)(dst + 8) = *(u32x4*)&tmp[8];
    }
}

// ---- main: R17 core + XCD-aware block swizzle + setprio on MFMA clusters ----
__global__ __launch_bounds__(256) void attn_fwd(
    const float* __restrict__ Q, const short* __restrict__ Kbf,
    const short* __restrict__ Vtb, const float* __restrict__ SL,
    float* __restrict__ O)
{
    const int bx = blockIdx.x;
    // XCD swizzle: bx&7 = kvh so each XCD's L2 caches ONE kv-head's K/V (1 MB).
    // i>>2 ascending = qt descending (heavy q-tiles still dispatch first).
    const int kvh = bx & 7;
    const int i   = bx >> 3;                    // 0..127 per kvh
    const int qt  = (NQT - 1) - (i >> 2);
    const int h   = kvh * 4 + (i & 3);
    const float slope  = SL[h];
    const float slope2 = slope * LOG2E;

    const int tid  = threadIdx.x;
    const int lane = tid & 63;
    const int w    = tid >> 6;                  // wave 0..3
    const int l16  = lane & 15;
    const int lq   = lane >> 4;

    __shared__ short Ks[2][BK * K_STRIDE];     // double-buffered K [k][d]
    __shared__ short VTs[2][HD * VT_STRIDE];   // double-buffered V^T [d][k]
    __shared__ short Ps[4][16 * P_STRIDE];     // per-wave P [q][k]

    const int qrow0 = qt * BQ + w * 16;
    const int q     = qrow0 + l16;             // this lane's q row (swapped layout)

    // ---- Q fragment (B-operand; scale*log2e folded in) ----
    bf16x8 qf[4];
    {
        const float* qp = Q + (size_t)q * QSTR + h * HD + lq * 8;
        #pragma unroll
        for (int d0 = 0; d0 < 4; ++d0) {
            f32x4 a = *(const f32x4*)(qp + d0 * 32);
            f32x4 b = *(const f32x4*)(qp + d0 * 32 + 4);
            u32x4 t;
            t[0] = cvt_pk_bf16(a[0] * QK_SCALE2, a[1] * QK_SCALE2);
            t[1] = cvt_pk_bf16(a[2] * QK_SCALE2, a[3] * QK_SCALE2);
            t[2] = cvt_pk_bf16(b[0] * QK_SCALE2, b[1] * QK_SCALE2);
            t[3] = cvt_pk_bf16(b[2] * QK_SCALE2, b[3] * QK_SCALE2);
            qf[d0] = as_bf16x8(t);
        }
    }
    // all-ones A fragment: mfma(ones, pf, sums) -> every row = colsum(P) = l(q)
    bf16x8 onesf;
    #pragma unroll
    for (int j = 0; j < 8; ++j) onesf[j] = (short)0x3f80;

    // acc holds O^T: acc[t][i] = O[q][t*16 + 4*lq + i]
    f32x4 acc[8];
    #pragma unroll
    for (int t = 0; t < 8; ++t) acc[t] = (f32x4){0.f, 0.f, 0.f, 0.f};
    f32x4 sums = (f32x4){0.f, 0.f, 0.f, 0.f};  // l accumulator (all elems equal)
    float m_ = -1e30f;                          // per-lane running max (one q/lane)

    const int kv_end = qt * BQ + BQ;
    int kb_start = 0;
    {   // ALiBi far-tile skip (weight <= e^-33 vs diagonal)
        float th = (float)(qt * BQ) - 31.0f - 45.0f / slope;
        int t = (int)floorf(th);
        kb_start = (t < 0) ? 0 : (((t >> 5) + 1) << 5);
    }

    // ---- staging thread mapping: bf16 sources, 16B chunks ----
    const int sr  = tid >> 4, scc = tid & 15;         // K rows sr, sr+16; chunk scc
    const int vd  = tid & 127, vrb = (tid >> 7) * 8;  // V^T row vd; k chunks vrb, vrb+16
    const short* Kst = Kbf + (size_t)kvh * S_LEN * HD + scc * 8;
    const short* Vst = Vtb + (size_t)(kvh * HD + vd) * S_LEN;

    u32x4 kreg[2], vreg[2];

    auto load_regs = [&](int kb) {
        #pragma unroll
        for (int s = 0; s < 2; ++s)
            kreg[s] = *(const u32x4*)(Kst + (size_t)(kb + sr + s * 16) * HD);
        #pragma unroll
        for (int s = 0; s < 2; ++s)
            vreg[s] = *(const u32x4*)(Vst + kb + vrb + s * 16);
    };

    auto store_tile = [&](int b) {
        #pragma unroll
        for (int s = 0; s < 2; ++s)
            *(u32x4*)&Ks[b][(sr + s * 16) * K_STRIDE + scc * 8] = kreg[s];
        #pragma unroll
        for (int s = 0; s < 2; ++s)
            *(u32x4*)&VTs[b][vd * VT_STRIDE + vrb + s * 16] = vreg[s];
    };

    load_regs(kb_start);
    store_tile(0);
    int cur = 0;

    for (int kb = kb_start; kb < kv_end; kb += BK) {
        // one barrier per tile; vmcnt NOT drained (prefetch spans barrier)
        asm volatile("s_waitcnt lgkmcnt(0)\n\ts_barrier" ::: "memory");

        const bool has_next = (kb + BK) < kv_end;
        if (has_next) load_regs(kb + BK);

        const bool live = (kb <= qrow0 + 15) &&
                          (slope * (float)(qrow0 - kb - 31) < 45.0f);
        if (live) {
            const short* Kc = &Ks[cur][0];
            const short* Vc = &VTs[cur][0];

            // ---- S^T = K·Q^T : A = K rows (k), B = Q (col = q = l16) ----
            f32x4 sc0 = (f32x4){0.f,0.f,0.f,0.f};   // k = kb + 4*lq + i
            f32x4 sc1 = (f32x4){0.f,0.f,0.f,0.f};   // k = kb + 16 + 4*lq + i
            __builtin_amdgcn_s_setprio(1);           // T5: keep matrix pipe fed
            #pragma unroll
            for (int d0 = 0; d0 < 4; ++d0) {
                bf16x8 kf0 = *(const bf16x8*)&Kc[l16 * K_STRIDE + d0 * 32 + lq * 8];
                bf16x8 kf1 = *(const bf16x8*)&Kc[(16 + l16) * K_STRIDE + d0 * 32 + lq * 8];
                sc0 = __builtin_amdgcn_mfma_f32_16x16x32_bf16(kf0, qf[d0], sc0, 0, 0, 0);
                sc1 = __builtin_amdgcn_mfma_f32_16x16x32_bf16(kf1, qf[d0], sc1, 0, 0, 0);
            }
            __builtin_amdgcn_s_setprio(0);

            // ---- bias + causal, all per-lane (q fixed = l16 col) ----
            const int kq0 = kb + 4 * lq - q;         // k - q at subtile A, i=0
            float s[8];
            #pragma unroll
            for (int i2 = 0; i2 < 4; ++i2) {
                int d0i = kq0 + i2, d1i = kq0 + 16 + i2;
                float b0 = __builtin_fmaf(slope2, (float)d0i, sc0[i2]);
                float b1 = __builtin_fmaf(slope2, (float)d1i, sc1[i2]);
                s[i2]     = (d0i > 0) ? -1e30f : b0;
                s[i2 + 4] = (d1i > 0) ? -1e30f : b1;
            }

            // ---- shuffle-free defer-max trigger: local max only ----
            float lm = fmaxf(fmaxf(fmaxf(s[0], s[1]), fmaxf(s[2], s[3])),
                             fmaxf(fmaxf(s[4], s[5]), fmaxf(s[6], s[7])));
            if (__any(lm > m_ + DTHR)) {
                // rare growth tile: full row reduce + rescale (row-uniform)
                float rm = lm;
                rm = fmaxf(rm, __shfl_xor(rm, 16));
                rm = fmaxf(rm, __shfl_xor(rm, 32));
                if (rm > m_ + DTHR) {
                    float alpha = exp2f(m_ - rm);
                    m_ = rm;
                    sums[0] *= alpha; sums[1] *= alpha;
                    sums[2] *= alpha; sums[3] *= alpha;
                    #pragma unroll
                    for (int t = 0; t < 8; ++t) {
                        acc[t][0] *= alpha; acc[t][1] *= alpha;
                        acc[t][2] *= alpha; acc[t][3] *= alpha;
                    }
                }
            }

            // ---- p = exp2(s - m); pack (sum comes from ones-MFMA) ----
            float p[8];
            #pragma unroll
            for (int j = 0; j < 8; ++j) p[j] = exp2f(s[j] - m_);

            u32x2 pa, pb;
            pa[0] = cvt_pk_bf16(p[0], p[1]); pa[1] = cvt_pk_bf16(p[2], p[3]);
            pb[0] = cvt_pk_bf16(p[4], p[5]); pb[1] = cvt_pk_bf16(p[6], p[7]);

            // ---- P[q][k] to LDS: two b64 writes, one b128 read (R10-proven) ----
            short* PsW = &Ps[w][0];
            *(u32x2*)&PsW[l16 * P_STRIDE + 4 * lq]      = pa;  // k = 4lq..4lq+3
            *(u32x2*)&PsW[l16 * P_STRIDE + 16 + 4 * lq] = pb;  // k = 16+4lq..
            asm volatile("s_waitcnt lgkmcnt(0)" ::: "memory");
            bf16x8 pf = *(const bf16x8*)&PsW[l16 * P_STRIDE + lq * 8]; // k=8lq..+7

            // ---- l-sum via ones-MFMA + PV, priority-boosted cluster ----
            __builtin_amdgcn_s_setprio(1);
            sums = __builtin_amdgcn_mfma_f32_16x16x32_bf16(onesf, pf, sums, 0, 0, 0);
            #pragma unroll
            for (int nt = 0; nt < 8; ++nt) {
                bf16x8 vf = *(const bf16x8*)&Vc[(nt * 16 + l16) * VT_STRIDE + lq * 8];
                acc[nt] = __builtin_amdgcn_mfma_f32_16x16x32_bf16(vf, pf, acc[nt], 0, 0, 0);
            }
            __builtin_amdgcn_s_setprio(0);
        }

        if (has_next) store_tile(cur ^ 1);
        cur ^= 1;
    }

    // ---- epilogue: acc[t] = O[q][t*16 + 4lq .. +3], contiguous f32x4 ----
    {
        float rl = 1.0f / sums[0];               // all elems equal = l(q)
        float* op = O + (size_t)q * QSTR + h * HD + 4 * lq;
        #pragma unroll
        for (int nt = 0; nt < 8; ++nt) {
            f32x4 o = acc[nt];
            o[0] *= rl; o[1] *= rl; o[2] *= rl; o[3] *= rl;
            *(f32x4*)(op + nt * 16) = o;
        }
    }
}

extern "C" void kernel_launch(void* const* d_in, const int* in_sizes, int n_in,
                              void* d_out, int out_size, void* d_ws, size_t ws_size,
                              hipStream_t stream) {
    const float* Q  = (const float*)d_in[0];
    const float* K  = (const float*)d_in[1];
    const float* V  = (const float*)d_in[2];
    const float* SL = (const float*)d_in[3];
    float* O = (float*)d_out;

    short* Kbf = (short*)d_ws;                                   // 4 MB
    short* Vtb = (short*)d_ws + (size_t)NKV * S_LEN * HD;        // 4 MB

    prep_kv<<<dim3(1536), dim3(256), 0, stream>>>(K, V, Kbf, Vtb);
    attn_fwd<<<dim3(NQT * NHEADS), dim3(256), 0, stream>>>(Q, Kbf, Vtb, SL, O);
}

// Round 22
// 88.889 us; speedup vs baseline: 2.2360x; 1.0294x over previous
//
#include <hip/hip_runtime.h>
#include <hip/hip_bf16.h>

#define S_LEN 2048
#define NHEADS 32
#define NKV 8
#define HD 128
#define QK_SCALE 0.08838834764831845f           // 1/sqrt(128)
#define LOG2E 1.4426950408889634f
#define QK_SCALE2 (QK_SCALE * LOG2E)            // folded into Q (log2 domain)
#define DTHR 11.5416f                           // defer-max threshold (8 nats in log2)

#define BQ 64                 // q rows per block (4 waves x 16)
#define BK 32                 // kv rows per tile
#define NQT (S_LEN / BQ)      // 32 q tiles
#define QSTR (NHEADS * HD)    // 4096
#define KSTR (NKV * HD)       // 1024

#define K_STRIDE 136          // LDS row stride (shorts) — R10-proven
#define VT_STRIDE 40          // R10-proven
#define P_STRIDE 40

typedef __attribute__((ext_vector_type(8))) short bf16x8;
typedef __attribute__((ext_vector_type(4))) float f32x4;
typedef __attribute__((ext_vector_type(4))) unsigned u32x4;
typedef __attribute__((ext_vector_type(2))) unsigned u32x2;

__device__ inline unsigned cvt_pk_bf16(float lo, float hi) {
    unsigned r;
    asm("v_cvt_pk_bf16_f32 %0, %1, %2" : "=v"(r) : "v"(lo), "v"(hi));
    return r;
}
__device__ inline bf16x8 as_bf16x8(u32x4 v) {
    union { u32x4 u; bf16x8 b; } c; c.u = v; return c.b;
}

// ---- merged pre-pass: K -> Kbf [kv][s][hd] bf16; V -> Vtb [kv][hd][s] bf16 ----
__global__ __launch_bounds__(256) void prep_kv(
    const float* __restrict__ K, const float* __restrict__ V,
    short* __restrict__ Kbf, short* __restrict__ Vtb)
{
    __shared__ short Ts[64][72];                 // used by V path only
    const int b = blockIdx.x;
    if (b < 1024) {
        // ---- K path (R15-proven): rows fragment-ready ----
        int g = b * 256 + threadIdx.x;           // [0, S*KV*16)
        int chunk = g & 15, kvh = (g >> 4) & 7, s = g >> 7;
        const float* in = K + (size_t)s * KSTR + kvh * HD + chunk * 8;
        f32x4 a = *(const f32x4*)in;
        f32x4 c = *(const f32x4*)(in + 4);
        u32x4 t;
        t[0] = cvt_pk_bf16(a[0], a[1]); t[1] = cvt_pk_bf16(a[2], a[3]);
        t[2] = cvt_pk_bf16(c[0], c[1]); t[3] = cvt_pk_bf16(c[2], c[3]);
        *(u32x4*)(Kbf + ((size_t)kvh * S_LEN + s) * HD + chunk * 8) = t;
    } else {
        // ---- V path (R8-verified): transpose to [kv][hd][s] ----
        int bv = b - 1024;                       // 512 = kvh(8) x db(2) x sb(32)
        int sb = bv & 31, db = (bv >> 5) & 1, kvh = bv >> 6;
        int t = threadIdx.x, r = t >> 2, c0 = (t & 3) * 16;

        const float* in = V + (size_t)(sb * 64 + r) * KSTR + kvh * HD + db * 64 + c0;
        f32x4 a0 = *(const f32x4*)in,        a1 = *(const f32x4*)(in + 4);
        f32x4 a2 = *(const f32x4*)(in + 8),  a3 = *(const f32x4*)(in + 12);
        u32x4 t0;
        t0[0] = cvt_pk_bf16(a0[0], a0[1]); t0[1] = cvt_pk_bf16(a0[2], a0[3]);
        t0[2] = cvt_pk_bf16(a1[0], a1[1]); t0[3] = cvt_pk_bf16(a1[2], a1[3]);
        *(u32x4*)&Ts[r][c0] = t0;
        t0[0] = cvt_pk_bf16(a2[0], a2[1]); t0[1] = cvt_pk_bf16(a2[2], a2[3]);
        t0[2] = cvt_pk_bf16(a3[0], a3[1]); t0[3] = cvt_pk_bf16(a3[2], a3[3]);
        *(u32x4*)&Ts[r][c0 + 8] = t0;
        __syncthreads();

        alignas(16) short tmp[16];
        #pragma unroll
        for (int j = 0; j < 16; ++j) tmp[j] = Ts[c0 + j][r];
        short* dst = Vtb + ((size_t)(kvh * HD + db * 64 + r)) * S_LEN + sb * 64 + c0;
        *(u32x4*)dst       = *(u32x4*)&tmp[0];
        *(u32x4*)(dst + 8) = *(u32x4*)&tmp[8];
    }
}

// ---- main: R17 core + XCD swizzle, descending-k, vf-hoist, no setprio ----
__global__ __launch_bounds__(256) void attn_fwd(
    const float* __restrict__ Q, const short* __restrict__ Kbf,
    const short* __restrict__ Vtb, const float* __restrict__ SL,
    float* __restrict__ O)
{
    const int bx = blockIdx.x;
    // XCD swizzle: bx&7 = kvh so each XCD's L2 caches ONE kv-head's K/V (1 MB).
    const int kvh = bx & 7;
    const int i   = bx >> 3;                    // 0..127 per kvh
    const int qt  = (NQT - 1) - (i >> 2);       // heavy q-tiles dispatch first
    const int h   = kvh * 4 + (i & 3);
    const float slope  = SL[h];
    const float slope2 = slope * LOG2E;

    const int tid  = threadIdx.x;
    const int lane = tid & 63;
    const int w    = tid >> 6;                  // wave 0..3
    const int l16  = lane & 15;
    const int lq   = lane >> 4;

    __shared__ short Ks[2][BK * K_STRIDE];     // double-buffered K [k][d]
    __shared__ short VTs[2][HD * VT_STRIDE];   // double-buffered V^T [d][k]
    __shared__ short Ps[4][16 * P_STRIDE];     // per-wave P [q][k]

    const int qrow0 = qt * BQ + w * 16;
    const int q     = qrow0 + l16;             // this lane's q row (swapped layout)

    // ---- Q fragment (B-operand; scale*log2e folded in) ----
    bf16x8 qf[4];
    {
        const float* qp = Q + (size_t)q * QSTR + h * HD + lq * 8;
        #pragma unroll
        for (int d0 = 0; d0 < 4; ++d0) {
            f32x4 a = *(const f32x4*)(qp + d0 * 32);
            f32x4 b = *(const f32x4*)(qp + d0 * 32 + 4);
            u32x4 t;
            t[0] = cvt_pk_bf16(a[0] * QK_SCALE2, a[1] * QK_SCALE2);
            t[1] = cvt_pk_bf16(a[2] * QK_SCALE2, a[3] * QK_SCALE2);
            t[2] = cvt_pk_bf16(b[0] * QK_SCALE2, b[1] * QK_SCALE2);
            t[3] = cvt_pk_bf16(b[2] * QK_SCALE2, b[3] * QK_SCALE2);
            qf[d0] = as_bf16x8(t);
        }
    }
    // all-ones A fragment: mfma(ones, pf, sums) -> every row = colsum(P) = l(q)
    bf16x8 onesf;
    #pragma unroll
    for (int j = 0; j < 8; ++j) onesf[j] = (short)0x3f80;

    // acc holds O^T: acc[t][i] = O[q][t*16 + 4*lq + i]
    f32x4 acc[8];
    #pragma unroll
    for (int t = 0; t < 8; ++t) acc[t] = (f32x4){0.f, 0.f, 0.f, 0.f};
    f32x4 sums = (f32x4){0.f, 0.f, 0.f, 0.f};  // l accumulator (all elems equal)
    float m_ = -1e30f;                          // per-lane running max (one q/lane)

    const int kv_end = qt * BQ + BQ;
    int kb_start = 0;
    {   // ALiBi far-tile skip (weight <= e^-33 vs diagonal)
        float th = (float)(qt * BQ) - 31.0f - 45.0f / slope;
        int t = (int)floorf(th);
        kb_start = (t < 0) ? 0 : (((t >> 5) + 1) << 5);
    }

    // ---- staging thread mapping: bf16 sources, 16B chunks ----
    const int sr  = tid >> 4, scc = tid & 15;         // K rows sr, sr+16; chunk scc
    const int vd  = tid & 127, vrb = (tid >> 7) * 8;  // V^T row vd; k chunks vrb, vrb+16
    const short* Kst = Kbf + (size_t)kvh * S_LEN * HD + scc * 8;
    const short* Vst = Vtb + (size_t)(kvh * HD + vd) * S_LEN;

    u32x4 kreg[2], vreg[2];

    auto load_regs = [&](int kb) {
        #pragma unroll
        for (int s = 0; s < 2; ++s)
            kreg[s] = *(const u32x4*)(Kst + (size_t)(kb + sr + s * 16) * HD);
        #pragma unroll
        for (int s = 0; s < 2; ++s)
            vreg[s] = *(const u32x4*)(Vst + kb + vrb + s * 16);
    };

    auto store_tile = [&](int b) {
        #pragma unroll
        for (int s = 0; s < 2; ++s)
            *(u32x4*)&Ks[b][(sr + s * 16) * K_STRIDE + scc * 8] = kreg[s];
        #pragma unroll
        for (int s = 0; s < 2; ++s)
            *(u32x4*)&VTs[b][vd * VT_STRIDE + vrb + s * 16] = vreg[s];
    };

    // ---- descending-k: first live tile per wave is its DIAGONAL tile, so m_
    //      initializes at ~the true row max and rescale almost never re-fires.
    const int kb_last = kv_end - BK;
    load_regs(kb_last);
    store_tile(0);
    int cur = 0;

    for (int kb = kb_last; kb >= kb_start; kb -= BK) {
        // one barrier per tile; vmcnt NOT drained (prefetch spans barrier)
        asm volatile("s_waitcnt lgkmcnt(0)\n\ts_barrier" ::: "memory");

        const bool has_next = (kb - BK) >= kb_start;
        if (has_next) load_regs(kb - BK);

        const bool live = (kb <= qrow0 + 15) &&
                          (slope * (float)(qrow0 - kb - 31) < 45.0f);
        if (live) {
            const short* Kc = &Ks[cur][0];
            const short* Vc = &VTs[cur][0];

            // ---- S^T = K·Q^T : A = K rows (k), B = Q (col = q = l16) ----
            f32x4 sc0 = (f32x4){0.f,0.f,0.f,0.f};   // k = kb + 4*lq + i
            f32x4 sc1 = (f32x4){0.f,0.f,0.f,0.f};   // k = kb + 16 + 4*lq + i
            #pragma unroll
            for (int d0 = 0; d0 < 4; ++d0) {
                bf16x8 kf0 = *(const bf16x8*)&Kc[l16 * K_STRIDE + d0 * 32 + lq * 8];
                bf16x8 kf1 = *(const bf16x8*)&Kc[(16 + l16) * K_STRIDE + d0 * 32 + lq * 8];
                sc0 = __builtin_amdgcn_mfma_f32_16x16x32_bf16(kf0, qf[d0], sc0, 0, 0, 0);
                sc1 = __builtin_amdgcn_mfma_f32_16x16x32_bf16(kf1, qf[d0], sc1, 0, 0, 0);
            }

            // ---- bias + causal, all per-lane (q fixed = l16 col) ----
            const int kq0 = kb + 4 * lq - q;         // k - q at subtile A, i=0
            float s[8];
            #pragma unroll
            for (int i2 = 0; i2 < 4; ++i2) {
                int d0i = kq0 + i2, d1i = kq0 + 16 + i2;
                float b0 = __builtin_fmaf(slope2, (float)d0i, sc0[i2]);
                float b1 = __builtin_fmaf(slope2, (float)d1i, sc1[i2]);
                s[i2]     = (d0i > 0) ? -1e30f : b0;
                s[i2 + 4] = (d1i > 0) ? -1e30f : b1;
            }

            // ---- shuffle-free defer-max trigger (rare after diagonal tile) ----
            float lm = fmaxf(fmaxf(fmaxf(s[0], s[1]), fmaxf(s[2], s[3])),
                             fmaxf(fmaxf(s[4], s[5]), fmaxf(s[6], s[7])));
            if (__any(lm > m_ + DTHR)) {
                float rm = lm;
                rm = fmaxf(rm, __shfl_xor(rm, 16));
                rm = fmaxf(rm, __shfl_xor(rm, 32));
                if (rm > m_ + DTHR) {
                    float alpha = exp2f(m_ - rm);
                    m_ = rm;
                    sums[0] *= alpha; sums[1] *= alpha;
                    sums[2] *= alpha; sums[3] *= alpha;
                    #pragma unroll
                    for (int t = 0; t < 8; ++t) {
                        acc[t][0] *= alpha; acc[t][1] *= alpha;
                        acc[t][2] *= alpha; acc[t][3] *= alpha;
                    }
                }
            }

            // ---- p = exp2(s - m); pack (sum comes from ones-MFMA) ----
            float p[8];
            #pragma unroll
            for (int j = 0; j < 8; ++j) p[j] = exp2f(s[j] - m_);

            u32x2 pa, pb;
            pa[0] = cvt_pk_bf16(p[0], p[1]); pa[1] = cvt_pk_bf16(p[2], p[3]);
            pb[0] = cvt_pk_bf16(p[4], p[5]); pb[1] = cvt_pk_bf16(p[6], p[7]);

            // ---- P[q][k] to LDS, then HOISTED vf reads overlap the drain ----
            short* PsW = &Ps[w][0];
            *(u32x2*)&PsW[l16 * P_STRIDE + 4 * lq]      = pa;  // k = 4lq..4lq+3
            *(u32x2*)&PsW[l16 * P_STRIDE + 16 + 4 * lq] = pb;  // k = 16+4lq..

            bf16x8 vf[8];                          // independent of P: issue now
            #pragma unroll
            for (int nt = 0; nt < 8; ++nt)
                vf[nt] = *(const bf16x8*)&Vc[(nt * 16 + l16) * VT_STRIDE + lq * 8];

            // LDS ops retire in-order: allow the 8 vf reads to stay in flight,
            // retire (at least) the 2 P-writes before reading pf back.
            asm volatile("s_waitcnt lgkmcnt(8)" ::: "memory");
            bf16x8 pf = *(const bf16x8*)&PsW[l16 * P_STRIDE + lq * 8]; // k=8lq..+7

            // ---- l-sum via ones-MFMA + PV (vf already in regs) ----
            sums = __builtin_amdgcn_mfma_f32_16x16x32_bf16(onesf, pf, sums, 0, 0, 0);
            #pragma unroll
            for (int nt = 0; nt < 8; ++nt)
                acc[nt] = __builtin_amdgcn_mfma_f32_16x16x32_bf16(vf[nt], pf, acc[nt], 0, 0, 0);
        }

        if (has_next) store_tile(cur ^ 1);
        cur ^= 1;
    }

    // ---- epilogue: acc[t] = O[q][t*16 + 4lq .. +3], contiguous f32x4 ----
    {
        float rl = 1.0f / sums[0];               // all elems equal = l(q)
        float* op = O + (size_t)q * QSTR + h * HD + 4 * lq;
        #pragma unroll
        for (int nt = 0; nt < 8; ++nt) {
            f32x4 o = acc[nt];
            o[0] *= rl; o[1] *= rl; o[2] *= rl; o[3] *= rl;
            *(f32x4*)(op + nt * 16) = o;
        }
    }
}

extern "C" void kernel_launch(void* const* d_in, const int* in_sizes, int n_in,
                              void* d_out, int out_size, void* d_ws, size_t ws_size,
                              hipStream_t stream) {
    const float* Q  = (const float*)d_in[0];
    const float* K  = (const float*)d_in[1];
    const float* V  = (const float*)d_in[2];
    const float* SL = (const float*)d_in[3];
    float* O = (float*)d_out;

    short* Kbf = (short*)d_ws;                                   // 4 MB
    short* Vtb = (short*)d_ws + (size_t)NKV * S_LEN * HD;        // 4 MB

    prep_kv<<<dim3(1536), dim3(256), 0, stream>>>(K, V, Kbf, Vtb);
    attn_fwd<<<dim3(NQT * NHEADS), dim3(256), 0, stream>>>(Q, Kbf, Vtb, SL, O);
}